// Round 2
// baseline (15321.291 us; speedup 1.0000x reference)
//
#include <hip/hip_runtime.h>

// B=16, T=256, IN=256, H=1024, L=4, 4 gates -> 4H=4096.
// ws (bytes): pre 64MB | seqA 16MB | seqB 16MB | hhi 8MB | hlo 8MB | ctr 128KB

typedef float f32x4 __attribute__((ext_vector_type(4)));
typedef short bf16x8 __attribute__((ext_vector_type(8)));

__device__ __forceinline__ unsigned short f2bf_rn(float x) {
    unsigned int u = __float_as_uint(x);
    u += 0x7FFFu + ((u >> 16) & 1u);          // round-to-nearest-even
    return (unsigned short)(u >> 16);
}
__device__ __forceinline__ float bf2f(unsigned short s) {
    return __uint_as_float(((unsigned int)s) << 16);
}
__device__ __forceinline__ float sigmoidf_(float x) { return 1.0f / (1.0f + __expf(-x)); }
__device__ __forceinline__ float tanhf_(float x) {
    float e = __expf(2.0f * x);
    return 1.0f - 2.0f / (e + 1.0f);
}

// ---------------------------------------------------------------------------
// pre[t][b][g*1024+j] = sum_k inp[b*T+t][k] * W[g][k][j] + bias[g*1024+j]
// fp32, 128x128 tile, BK=16, 256 threads, 8x8 micro-tile.
// ---------------------------------------------------------------------------
__global__ __launch_bounds__(256)
void pre_gemm(const float* __restrict__ A, const float* __restrict__ W,
              const float* __restrict__ bias, float* __restrict__ out, int K)
{
    __shared__ float As[16][132];   // [k][m]
    __shared__ float Bs[16][132];   // [k][n]

    const int tid = threadIdx.x;
    const int m0 = blockIdx.y << 7;
    const int n0 = blockIdx.x << 7;           // tile stays inside one gate
    const int g  = n0 >> 10;
    const int jb = n0 & 1023;
    const float* Wg = W + (size_t)g * K * 1024 + jb;

    const int tx = tid & 15;
    const int ty = tid >> 4;
    const int alk = tid & 15;
    const int alm = tid >> 4;
    const int bln = tid & 127;
    const int blkk = tid >> 7;

    float acc[8][8];
#pragma unroll
    for (int i = 0; i < 8; ++i)
#pragma unroll
        for (int j = 0; j < 8; ++j) acc[i][j] = 0.f;

    for (int k0 = 0; k0 < K; k0 += 16) {
        __syncthreads();
#pragma unroll
        for (int r = 0; r < 8; ++r) {
            int m = alm + (r << 4);
            As[alk][m] = A[(size_t)(m0 + m) * K + (k0 + alk)];
        }
#pragma unroll
        for (int r = 0; r < 8; ++r) {
            int kk = blkk + (r << 1);
            Bs[kk][bln] = Wg[(size_t)(k0 + kk) * 1024 + bln];
        }
        __syncthreads();
#pragma unroll
        for (int k = 0; k < 16; ++k) {
            float a[8], bb[8];
            *(f32x4*)&a[0]  = *(const f32x4*)&As[k][ty << 2];
            *(f32x4*)&a[4]  = *(const f32x4*)&As[k][64 + (ty << 2)];
            *(f32x4*)&bb[0] = *(const f32x4*)&Bs[k][tx << 2];
            *(f32x4*)&bb[4] = *(const f32x4*)&Bs[k][64 + (tx << 2)];
#pragma unroll
            for (int i = 0; i < 8; ++i)
#pragma unroll
                for (int j = 0; j < 8; ++j)
                    acc[i][j] = fmaf(a[i], bb[j], acc[i][j]);
        }
    }

    float bj[8];
#pragma unroll
    for (int j = 0; j < 8; ++j) {
        int nloc = (j < 4) ? ((tx << 2) + j) : (64 + (tx << 2) + (j - 4));
        bj[j] = bias[n0 + nloc];
    }
#pragma unroll
    for (int i = 0; i < 8; ++i) {
        int mloc = (i < 4) ? ((ty << 2) + i) : (64 + (ty << 2) + (i - 4));
        int m = m0 + mloc;
        int bidx = m >> 8;                    // b = m / 256
        int tt   = m & 255;                   // t = m % 256
        float* orow = out + ((size_t)((tt << 4) + bidx) << 12) + n0;
#pragma unroll
        for (int j = 0; j < 8; ++j) {
            int nloc = (j < 4) ? ((tx << 2) + j) : (64 + (tx << 2) + (j - 4));
            orow[nloc] = acc[i][j] + bj[j];
        }
    }
}

// ---------------------------------------------------------------------------
// Persistent cooperative LSTM scan, one layer. 256 wgs x 256 threads.
// wg owns cols j=wg*4..wg*4+3 x 4 gates (16 MFMA output cols). Wh split into
// 3 bf16 planes held in REGISTERS (96 VGPR/lane). h exchanged via T-deep
// global bf16 hi/lo planes (each region read once -> always cold in L2; no
// cache invalidation needed). 5 split-precision MFMA passes give fp32-grade
// accuracy. Custom per-step counter barrier (release add + relaxed spin).
// ---------------------------------------------------------------------------
__global__ __launch_bounds__(256)
void lstm_scan(const float* __restrict__ pre,   // [T][B][4096]
               const float* __restrict__ Wh,    // [4][1024][1024] this layer
               float* __restrict__ seq_out,     // [B][T][1024]
               unsigned short* __restrict__ hhi, // [T][16][1024] bf16 hi plane
               unsigned short* __restrict__ hlo, // [T][16][1024] bf16 lo plane
               int* __restrict__ ctr,            // [256] slots, stride 32 ints
               float* __restrict__ final_out,    // [16][1024]
               int is_last)
{
    const int wg   = blockIdx.x;
    const int tid  = threadIdx.x;
    const int wv   = tid >> 6;        // wave 0..3 owns k-range [wv*256, wv*256+256)
    const int lane = tid & 63;
    const int bc   = lane & 15;       // A-frag m (=batch) and B-frag n (=gate col)
    const int quad = lane >> 4;

    __shared__ float red[4][64][4];   // cross-wave C reduction
    __shared__ float gsh[16][17];     // gate exchange [b][g*4+jl]

    // ---- one-time: load Wh slice, 3-term bf16 split into registers ----
    const int g   = bc >> 2;
    const int col = (wg << 2) + (bc & 3);
    bf16x8 Whi[8], Wmi[8], Wlo[8];
#pragma unroll
    for (int ck = 0; ck < 8; ++ck) {
#pragma unroll
        for (int j = 0; j < 8; ++j) {
            int k = (wv << 8) + (ck << 5) + (quad << 3) + j;
            float w = Wh[((size_t)g << 20) + ((size_t)k << 10) + col];
            unsigned short hi = f2bf_rn(w);
            float r1 = w - bf2f(hi);          // exact
            unsigned short mi = f2bf_rn(r1);
            float r2 = r1 - bf2f(mi);         // exact
            unsigned short lo = f2bf_rn(r2);
            Whi[ck][j] = (short)hi;
            Wmi[ck][j] = (short)mi;
            Wlo[ck][j] = (short)lo;
        }
    }

    float creg = 0.f;   // cell state for (b=lane>>2, jl=lane&3); wave-0 lanes only

    for (int t = 0; t < 256; ++t) {
        // prefetch this step's pre (independent of the barrier -> overlaps spin)
        float pr[4];
        if (wv == 0) {
            const float* pp = pre + ((size_t)t << 16) + ((size_t)(bc >> 2) << 10)
                              + (wg << 2) + (bc & 3);
#pragma unroll
            for (int r = 0; r < 4; ++r)
                pr[r] = pp[(size_t)((quad << 2) + r) << 12];
        }

        if (t > 0) {
            if (tid == 0) {
                while (__hip_atomic_load(&ctr[(t - 1) << 5], __ATOMIC_RELAXED,
                                         __HIP_MEMORY_SCOPE_AGENT) < 256)
                    __builtin_amdgcn_s_sleep(1);
            }
        }
        __syncthreads();                 // releases block; also red[] WAR guard
        asm volatile("" ::: "memory");   // no load hoisting above the spin

        f32x4 acc0 = {0.f, 0.f, 0.f, 0.f};
        f32x4 acc1 = {0.f, 0.f, 0.f, 0.f};
        if (t > 0) {
            const size_t pb = ((size_t)(t - 1) << 14) + ((size_t)bc << 10) + (wv << 8);
            const unsigned short* ph = hhi + pb;
            const unsigned short* pl = hlo + pb;
            bf16x8 ahi[8], alo[8];
#pragma unroll
            for (int ck = 0; ck < 8; ++ck) {
                ahi[ck] = *(const bf16x8*)(ph + (ck << 5) + (quad << 3));
                alo[ck] = *(const bf16x8*)(pl + (ck << 5) + (quad << 3));
            }
            // 5 split-precision passes: hi*hi + hi*mid + hi*lo + lo*hi + lo*mid
#pragma unroll
            for (int ck = 0; ck < 8; ++ck) {
                if (ck & 1) {
                    acc1 = __builtin_amdgcn_mfma_f32_16x16x32_bf16(ahi[ck], Whi[ck], acc1, 0, 0, 0);
                    acc1 = __builtin_amdgcn_mfma_f32_16x16x32_bf16(ahi[ck], Wmi[ck], acc1, 0, 0, 0);
                    acc1 = __builtin_amdgcn_mfma_f32_16x16x32_bf16(ahi[ck], Wlo[ck], acc1, 0, 0, 0);
                    acc1 = __builtin_amdgcn_mfma_f32_16x16x32_bf16(alo[ck], Whi[ck], acc1, 0, 0, 0);
                    acc1 = __builtin_amdgcn_mfma_f32_16x16x32_bf16(alo[ck], Wmi[ck], acc1, 0, 0, 0);
                } else {
                    acc0 = __builtin_amdgcn_mfma_f32_16x16x32_bf16(ahi[ck], Whi[ck], acc0, 0, 0, 0);
                    acc0 = __builtin_amdgcn_mfma_f32_16x16x32_bf16(ahi[ck], Wmi[ck], acc0, 0, 0, 0);
                    acc0 = __builtin_amdgcn_mfma_f32_16x16x32_bf16(ahi[ck], Wlo[ck], acc0, 0, 0, 0);
                    acc0 = __builtin_amdgcn_mfma_f32_16x16x32_bf16(alo[ck], Whi[ck], acc0, 0, 0, 0);
                    acc0 = __builtin_amdgcn_mfma_f32_16x16x32_bf16(alo[ck], Wmi[ck], acc0, 0, 0, 0);
                }
            }
        }
        f32x4 acc = acc0 + acc1;
        *(f32x4*)&red[wv][lane][0] = acc;
        __syncthreads();

        if (wv == 0) {
            f32x4 s0 = *(const f32x4*)&red[0][lane][0];
            f32x4 s1 = *(const f32x4*)&red[1][lane][0];
            f32x4 s2 = *(const f32x4*)&red[2][lane][0];
            f32x4 s3 = *(const f32x4*)&red[3][lane][0];
            f32x4 s = (s0 + s1) + (s2 + s3);
            // C layout: col = lane&15 (=bc), row = quad*4 + r (=batch)
#pragma unroll
            for (int r = 0; r < 4; ++r)
                gsh[(quad << 2) + r][bc] = s[r] + pr[r];

            // gates: lane owns (b2 = lane>>2, jl2 = lane&3); LDS in-order per wave
            const int b2 = lane >> 2, jl2 = lane & 3;
            float fg = sigmoidf_(gsh[b2][jl2]);           // forget
            float ig = sigmoidf_(gsh[b2][4 + jl2]);       // input (percent)
            float pg = tanhf_(gsh[b2][8 + jl2]);          // input (potential)
            float og = sigmoidf_(gsh[b2][12 + jl2]);      // output (old h)
            creg = fg * creg + ig * pg;
            float h = tanhf_(creg) * og;

            const int j = (wg << 2) + jl2;
            unsigned short hh = f2bf_rn(h);
            unsigned short hl = f2bf_rn(h - bf2f(hh));    // exact residual, then rne
            size_t pidx = ((size_t)t << 14) + ((size_t)b2 << 10) + j;
            // device-scope stores: write through non-coherent XCD L2 to LLC
            __hip_atomic_store(&hhi[pidx], hh, __ATOMIC_RELAXED, __HIP_MEMORY_SCOPE_AGENT);
            __hip_atomic_store(&hlo[pidx], hl, __ATOMIC_RELAXED, __HIP_MEMORY_SCOPE_AGENT);
            seq_out[((size_t)((b2 << 8) + t) << 10) + j] = h;
            if (is_last && t == 255) final_out[((size_t)b2 << 10) + j] = h;

            // release-add: s_waitcnt vmcnt(0) covers ALL wave-0 stores above
            if (lane == 0)
                __hip_atomic_fetch_add(&ctr[t << 5], 1, __ATOMIC_RELEASE,
                                       __HIP_MEMORY_SCOPE_AGENT);
        }
    }
}

// ---------------------------------------------------------------------------
extern "C" void kernel_launch(void* const* d_in, const int* in_sizes, int n_in,
                              void* d_out, int out_size, void* d_ws, size_t ws_size,
                              hipStream_t stream)
{
    (void)in_sizes; (void)n_in; (void)out_size; (void)ws_size;

    const float* x    = (const float*)d_in[0];   // [16][256][256]
    const float* Wh   = (const float*)d_in[1];   // [4][4][1024][1024]
    const float* Wx0  = (const float*)d_in[2];   // [4][256][1024]
    const float* Wx   = (const float*)d_in[3];   // [3][4][1024][1024]
    const float* bias = (const float*)d_in[4];   // [4][4][1024]

    float* pre  = (float*)d_ws;                    // 16,777,216 f (64 MB)
    float* seqA = pre + 16777216;                  // 4,194,304 f
    float* seqB = seqA + 4194304;                  // 4,194,304 f
    unsigned short* hhi = (unsigned short*)(seqB + 4194304);   // 4,194,304 u16
    unsigned short* hlo = hhi + 4194304;                       // 4,194,304 u16
    int* ctr = (int*)(hlo + 4194304);              // 4 layers x 256 slots x 32 ints

    float* fout = (float*)d_out;

    hipMemsetAsync(ctr, 0, (size_t)4 * 256 * 32 * sizeof(int), stream);

    const dim3 blk(256);
    const dim3 ggrid(32, 32);
    const size_t WLAYER = (size_t)4 * 1024 * 1024;

    for (int l = 0; l < 4; ++l) {
        const float* inp = (l == 0) ? x : ((l & 1) ? seqA : seqB);
        float* outp      = (l & 1) ? seqB : seqA;
        const float* wx  = (l == 0) ? Wx0 : (Wx + (size_t)(l - 1) * WLAYER);
        int K            = (l == 0) ? 256 : 1024;

        pre_gemm<<<ggrid, blk, 0, stream>>>(inp, wx, bias + (size_t)l * 4096, pre, K);

        const float* p = pre;
        const float* wh = Wh + (size_t)l * WLAYER;
        float* so = outp;
        unsigned short* phi = hhi;
        unsigned short* plo = hlo;
        int* pc = ctr + (size_t)l * 256 * 32;
        int last = (l == 3);
        void* args[] = { (void*)&p, (void*)&wh, (void*)&so, (void*)&phi,
                         (void*)&plo, (void*)&pc, (void*)&fout, (void*)&last };
        hipLaunchCooperativeKernel((void*)lstm_scan, dim3(256), dim3(256), args, 0, stream);
    }
}

// Round 3
// 9096.726 us; speedup vs baseline: 1.6843x; 1.6843x over previous
//
#include <hip/hip_runtime.h>

// B=16, T=256, IN=256, H=1024, L=4, 4 gates -> 4H=4096.
// ws (floats): pre 16,777,216 | seqA 4,194,304 | seqB 4,194,304
//              | hhi 2,097,152 | hlo 2,097,152 (u16 halves)
//              | ctr_l1 4*131072 ints | ctr_root 4*8192 ints   (~114.3 MB)

typedef float f32x4 __attribute__((ext_vector_type(4)));
typedef short bf16x8 __attribute__((ext_vector_type(8)));

__device__ __forceinline__ unsigned short f2bf_rn(float x) {
    unsigned int u = __float_as_uint(x);
    u += 0x7FFFu + ((u >> 16) & 1u);          // round-to-nearest-even
    return (unsigned short)(u >> 16);
}
__device__ __forceinline__ float bf2f(unsigned short s) {
    return __uint_as_float(((unsigned int)s) << 16);
}
__device__ __forceinline__ float sigmoidf_(float x) { return 1.0f / (1.0f + __expf(-x)); }
__device__ __forceinline__ float tanhf_(float x) {
    float e = __expf(2.0f * x);
    return 1.0f - 2.0f / (e + 1.0f);
}

// ---------------------------------------------------------------------------
// pre[t][b][g*1024+j] = sum_k inp[b*T+t][k] * W[g][k][j] + bias[g*1024+j]
// fp32, 128x128 tile, BK=16, 256 threads, 8x8 micro-tile. (unchanged from R2)
// ---------------------------------------------------------------------------
__global__ __launch_bounds__(256)
void pre_gemm(const float* __restrict__ A, const float* __restrict__ W,
              const float* __restrict__ bias, float* __restrict__ out, int K)
{
    __shared__ float As[16][132];   // [k][m]
    __shared__ float Bs[16][132];   // [k][n]

    const int tid = threadIdx.x;
    const int m0 = blockIdx.y << 7;
    const int n0 = blockIdx.x << 7;
    const int g  = n0 >> 10;
    const int jb = n0 & 1023;
    const float* Wg = W + (size_t)g * K * 1024 + jb;

    const int tx = tid & 15;
    const int ty = tid >> 4;
    const int alk = tid & 15;
    const int alm = tid >> 4;
    const int bln = tid & 127;
    const int blkk = tid >> 7;

    float acc[8][8];
#pragma unroll
    for (int i = 0; i < 8; ++i)
#pragma unroll
        for (int j = 0; j < 8; ++j) acc[i][j] = 0.f;

    for (int k0 = 0; k0 < K; k0 += 16) {
        __syncthreads();
#pragma unroll
        for (int r = 0; r < 8; ++r) {
            int m = alm + (r << 4);
            As[alk][m] = A[(size_t)(m0 + m) * K + (k0 + alk)];
        }
#pragma unroll
        for (int r = 0; r < 8; ++r) {
            int kk = blkk + (r << 1);
            Bs[kk][bln] = Wg[(size_t)(k0 + kk) * 1024 + bln];
        }
        __syncthreads();
#pragma unroll
        for (int k = 0; k < 16; ++k) {
            float a[8], bb[8];
            *(f32x4*)&a[0]  = *(const f32x4*)&As[k][ty << 2];
            *(f32x4*)&a[4]  = *(const f32x4*)&As[k][64 + (ty << 2)];
            *(f32x4*)&bb[0] = *(const f32x4*)&Bs[k][tx << 2];
            *(f32x4*)&bb[4] = *(const f32x4*)&Bs[k][64 + (tx << 2)];
#pragma unroll
            for (int i = 0; i < 8; ++i)
#pragma unroll
                for (int j = 0; j < 8; ++j)
                    acc[i][j] = fmaf(a[i], bb[j], acc[i][j]);
        }
    }

    float bj[8];
#pragma unroll
    for (int j = 0; j < 8; ++j) {
        int nloc = (j < 4) ? ((tx << 2) + j) : (64 + (tx << 2) + (j - 4));
        bj[j] = bias[n0 + nloc];
    }
#pragma unroll
    for (int i = 0; i < 8; ++i) {
        int mloc = (i < 4) ? ((ty << 2) + i) : (64 + (ty << 2) + (i - 4));
        int m = m0 + mloc;
        int bidx = m >> 8;
        int tt   = m & 255;
        float* orow = out + ((size_t)((tt << 4) + bidx) << 12) + n0;
#pragma unroll
        for (int j = 0; j < 8; ++j) {
            int nloc = (j < 4) ? ((tx << 2) + j) : (64 + (tx << 2) + (j - 4));
            orow[nloc] = acc[i][j] + bj[j];
        }
    }
}

// ---------------------------------------------------------------------------
// Persistent cooperative LSTM scan, one layer. 256 wgs x 256 threads.
// R3 change: barrier = two-level relaxed atomic tree + explicit
// s_waitcnt vmcnt(0); NO release ordering (avoids buffer_wbl2 L2 writeback),
// 16-way (not 256-way) same-address contention.
// h correctness across XCDs: hhi/hlo are T-deep write-once/read-once regions
// written with agent-scope (write-through) stores -> consumer caches can
// never hold a stale copy.
// ---------------------------------------------------------------------------
__global__ __launch_bounds__(256)
void lstm_scan(const float* __restrict__ pre,    // [T][B][4096]
               const float* __restrict__ Wh,     // [4][1024][1024] this layer
               float* __restrict__ seq_out,      // [B][T][1024]
               unsigned short* __restrict__ hhi, // [T][16][1024] bf16 hi plane
               unsigned short* __restrict__ hlo, // [T][16][1024] bf16 lo plane
               int* __restrict__ ctr_l1,         // [256 t][16 grp] stride-32 ints
               int* __restrict__ ctr_root,       // [256 t] stride-32 ints
               float* __restrict__ final_out,    // [16][1024]
               int is_last)
{
    const int wg   = blockIdx.x;
    const int tid  = threadIdx.x;
    const int wv   = tid >> 6;        // wave 0..3 owns k-range [wv*256, +256)
    const int lane = tid & 63;
    const int bc   = lane & 15;       // A-frag m (=batch) / B-frag n (=gate col)
    const int quad = lane >> 4;

    __shared__ float red[4][64][4];   // cross-wave C reduction
    __shared__ float gsh[16][17];     // gate exchange [b][g*4+jl]

    // ---- one-time: load Wh slice, 3-term bf16 split into registers ----
    const int g   = bc >> 2;
    const int col = (wg << 2) + (bc & 3);
    bf16x8 Whi[8], Wmi[8], Wlo[8];
#pragma unroll
    for (int ck = 0; ck < 8; ++ck) {
#pragma unroll
        for (int j = 0; j < 8; ++j) {
            int k = (wv << 8) + (ck << 5) + (quad << 3) + j;
            float w = Wh[((size_t)g << 20) + ((size_t)k << 10) + col];
            unsigned short hi = f2bf_rn(w);
            float r1 = w - bf2f(hi);          // exact
            unsigned short mi = f2bf_rn(r1);
            float r2 = r1 - bf2f(mi);         // exact
            unsigned short lo = f2bf_rn(r2);
            Whi[ck][j] = (short)hi;
            Wmi[ck][j] = (short)mi;
            Wlo[ck][j] = (short)lo;
        }
    }

    float creg = 0.f;   // cell state for (b=lane>>2, jl=lane&3); wave-0 lanes

    for (int t = 0; t < 256; ++t) {
        // prefetch this step's pre (barrier-independent -> overlaps the spin)
        float pr[4];
        if (wv == 0) {
            const float* pp = pre + ((size_t)t << 16) + ((size_t)(bc >> 2) << 10)
                              + (wg << 2) + (bc & 3);
#pragma unroll
            for (int r = 0; r < 4; ++r)
                pr[r] = pp[(size_t)((quad << 2) + r) << 12];
        }

        if (t > 0) {
            if (tid == 0) {
                while (__hip_atomic_load(&ctr_root[(t - 1) << 5], __ATOMIC_RELAXED,
                                         __HIP_MEMORY_SCOPE_AGENT) < 16)
                    __builtin_amdgcn_s_sleep(1);
            }
        }
        __syncthreads();
        asm volatile("" ::: "memory");

        f32x4 acc0 = {0.f, 0.f, 0.f, 0.f};
        f32x4 acc1 = {0.f, 0.f, 0.f, 0.f};
        if (t > 0) {
            const size_t pb = ((size_t)(t - 1) << 14) + ((size_t)bc << 10) + (wv << 8);
            const unsigned short* ph = hhi + pb;
            const unsigned short* pl = hlo + pb;
            bf16x8 ahi[8], alo[8];
#pragma unroll
            for (int ck = 0; ck < 8; ++ck) {
                ahi[ck] = *(const bf16x8*)(ph + (ck << 5) + (quad << 3));
                alo[ck] = *(const bf16x8*)(pl + (ck << 5) + (quad << 3));
            }
            // 5 split passes: hi*hi + hi*mid + hi*lo + lo*hi + lo*mid
#pragma unroll
            for (int ck = 0; ck < 8; ++ck) {
                if (ck & 1) {
                    acc1 = __builtin_amdgcn_mfma_f32_16x16x32_bf16(ahi[ck], Whi[ck], acc1, 0, 0, 0);
                    acc1 = __builtin_amdgcn_mfma_f32_16x16x32_bf16(ahi[ck], Wmi[ck], acc1, 0, 0, 0);
                    acc1 = __builtin_amdgcn_mfma_f32_16x16x32_bf16(ahi[ck], Wlo[ck], acc1, 0, 0, 0);
                    acc1 = __builtin_amdgcn_mfma_f32_16x16x32_bf16(alo[ck], Whi[ck], acc1, 0, 0, 0);
                    acc1 = __builtin_amdgcn_mfma_f32_16x16x32_bf16(alo[ck], Wmi[ck], acc1, 0, 0, 0);
                } else {
                    acc0 = __builtin_amdgcn_mfma_f32_16x16x32_bf16(ahi[ck], Whi[ck], acc0, 0, 0, 0);
                    acc0 = __builtin_amdgcn_mfma_f32_16x16x32_bf16(ahi[ck], Wmi[ck], acc0, 0, 0, 0);
                    acc0 = __builtin_amdgcn_mfma_f32_16x16x32_bf16(ahi[ck], Wlo[ck], acc0, 0, 0, 0);
                    acc0 = __builtin_amdgcn_mfma_f32_16x16x32_bf16(alo[ck], Whi[ck], acc0, 0, 0, 0);
                    acc0 = __builtin_amdgcn_mfma_f32_16x16x32_bf16(alo[ck], Wmi[ck], acc0, 0, 0, 0);
                }
            }
        }
        f32x4 acc = acc0 + acc1;
        *(f32x4*)&red[wv][lane][0] = acc;
        __syncthreads();

        if (wv == 0) {
            f32x4 s0 = *(const f32x4*)&red[0][lane][0];
            f32x4 s1 = *(const f32x4*)&red[1][lane][0];
            f32x4 s2 = *(const f32x4*)&red[2][lane][0];
            f32x4 s3 = *(const f32x4*)&red[3][lane][0];
            f32x4 s = (s0 + s1) + (s2 + s3);
            // C layout: col = lane&15 (=bc), row = quad*4 + r (=batch)
#pragma unroll
            for (int r = 0; r < 4; ++r)
                gsh[(quad << 2) + r][bc] = s[r] + pr[r];

            const int b2 = lane >> 2, jl2 = lane & 3;
            float fg = sigmoidf_(gsh[b2][jl2]);           // forget
            float ig = sigmoidf_(gsh[b2][4 + jl2]);       // input (percent)
            float pg = tanhf_(gsh[b2][8 + jl2]);          // input (potential)
            float og = sigmoidf_(gsh[b2][12 + jl2]);      // output (old h)
            creg = fg * creg + ig * pg;
            float h = tanhf_(creg) * og;

            const int j = (wg << 2) + jl2;
            unsigned short hh = f2bf_rn(h);
            unsigned short hl = f2bf_rn(h - bf2f(hh));
            size_t pidx = ((size_t)t << 14) + ((size_t)b2 << 10) + j;
            // agent-scope write-through stores: visible at the LLC, never
            // dirty in the producer's (non-coherent) XCD L2
            __hip_atomic_store(&hhi[pidx], hh, __ATOMIC_RELAXED, __HIP_MEMORY_SCOPE_AGENT);
            __hip_atomic_store(&hlo[pidx], hl, __ATOMIC_RELAXED, __HIP_MEMORY_SCOPE_AGENT);
            seq_out[((size_t)((b2 << 8) + t) << 10) + j] = h;   // next dispatch only
            if (is_last && t == 255) final_out[((size_t)b2 << 10) + j] = h;

            // drain ALL outstanding vmem (h stores reach the coherence point);
            // no release ordering -> no buffer_wbl2 L2 writeback
            __builtin_amdgcn_s_waitcnt(0);

            if (lane == 0) {
                const int grp = wg >> 4;
                int old = __hip_atomic_fetch_add(&ctr_l1[((t << 4) + grp) << 5], 1,
                                                 __ATOMIC_RELAXED,
                                                 __HIP_MEMORY_SCOPE_AGENT);
                if (old == 15)
                    __hip_atomic_fetch_add(&ctr_root[t << 5], 1,
                                           __ATOMIC_RELAXED,
                                           __HIP_MEMORY_SCOPE_AGENT);
            }
        }
    }
}

// ---------------------------------------------------------------------------
extern "C" void kernel_launch(void* const* d_in, const int* in_sizes, int n_in,
                              void* d_out, int out_size, void* d_ws, size_t ws_size,
                              hipStream_t stream)
{
    (void)in_sizes; (void)n_in; (void)out_size; (void)ws_size;

    const float* x    = (const float*)d_in[0];   // [16][256][256]
    const float* Wh   = (const float*)d_in[1];   // [4][4][1024][1024]
    const float* Wx0  = (const float*)d_in[2];   // [4][256][1024]
    const float* Wx   = (const float*)d_in[3];   // [3][4][1024][1024]
    const float* bias = (const float*)d_in[4];   // [4][4][1024]

    float* pre  = (float*)d_ws;                    // 16,777,216 f
    float* seqA = pre + 16777216;                  // 4,194,304 f
    float* seqB = seqA + 4194304;                  // 4,194,304 f
    unsigned short* hhi = (unsigned short*)(seqB + 4194304);   // 4,194,304 u16
    unsigned short* hlo = hhi + 4194304;                       // 4,194,304 u16
    int* ctr = (int*)(hlo + 4194304);
    // per layer: l1 = 256*16*32 ints (512KB), root = 256*32 ints (32KB)
    const size_t L1_PER_LAYER = 256 * 16 * 32;
    const size_t RT_PER_LAYER = 256 * 32;

    float* fout = (float*)d_out;

    hipMemsetAsync(ctr, 0, 4 * (L1_PER_LAYER + RT_PER_LAYER) * sizeof(int), stream);

    const dim3 blk(256);
    const dim3 ggrid(32, 32);
    const size_t WLAYER = (size_t)4 * 1024 * 1024;

    for (int l = 0; l < 4; ++l) {
        const float* inp = (l == 0) ? x : ((l & 1) ? seqA : seqB);
        float* outp      = (l & 1) ? seqB : seqA;
        const float* wx  = (l == 0) ? Wx0 : (Wx + (size_t)(l - 1) * WLAYER);
        int K            = (l == 0) ? 256 : 1024;

        pre_gemm<<<ggrid, blk, 0, stream>>>(inp, wx, bias + (size_t)l * 4096, pre, K);

        const float* p = pre;
        const float* wh = Wh + (size_t)l * WLAYER;
        float* so = outp;
        unsigned short* phi = hhi;
        unsigned short* plo = hlo;
        int* pl1 = ctr + (size_t)l * (L1_PER_LAYER + RT_PER_LAYER);
        int* prt = pl1 + L1_PER_LAYER;
        int last = (l == 3);
        void* args[] = { (void*)&p, (void*)&wh, (void*)&so, (void*)&phi,
                         (void*)&plo, (void*)&pl1, (void*)&prt,
                         (void*)&fout, (void*)&last };
        hipLaunchCooperativeKernel((void*)lstm_scan, dim3(256), dim3(256), args, 0, stream);
    }
}